// Round 3
// baseline (16.804 us; speedup 1.0000x reference)
//
#include <hip/hip_runtime.h>

// QuantumSelfAttention: analytic reduction.
// P(|1> on qubit 0) = sin^2(theta0/2), theta0 = features[b,n,0] (row stride 64 f32).
// Strided gather: 1 float per 256 B, 4 rows/thread for MLP.
// Plain (cached) loads: input is 128 MiB and fits L3; graph-replay timing means
// warm replays can be served from Infinity Cache -- nt hint would forbid that.

__global__ __launch_bounds__(256) void qsa_p1_kernel(
    const float* __restrict__ feat, float* __restrict__ out) {
    int base = blockIdx.x * 1024 + threadIdx.x;
    float th0 = feat[(size_t)(base        ) * 64];
    float th1 = feat[(size_t)(base +  256 ) * 64];
    float th2 = feat[(size_t)(base +  512 ) * 64];
    float th3 = feat[(size_t)(base +  768 ) * 64];
    float s0 = __sinf(0.5f * th0);
    float s1 = __sinf(0.5f * th1);
    float s2 = __sinf(0.5f * th2);
    float s3 = __sinf(0.5f * th3);
    out[base]       = s0 * s0;
    out[base + 256] = s1 * s1;
    out[base + 512] = s2 * s2;
    out[base + 768] = s3 * s3;
}

extern "C" void kernel_launch(void* const* d_in, const int* in_sizes, int n_in,
                              void* d_out, int out_size, void* d_ws, size_t ws_size,
                              hipStream_t stream) {
    const float* feat = (const float*)d_in[0];   // [64, 8192, 64] f32
    float* out = (float*)d_out;                  // [64, 8192] f32
    int n = out_size;                            // 524288 (multiple of 1024)
    const int threads = 256;
    int blocks = n / 1024;                       // 512
    qsa_p1_kernel<<<blocks, threads, 0, stream>>>(feat, out);
}

// Round 4
// 15.592 us; speedup vs baseline: 1.0777x; 1.0777x over previous
//
#include <hip/hip_runtime.h>

// QuantumSelfAttention: analytic reduction.
// P(|1> on qubit 0) = sin^2(theta0/2), theta0 = features[b,n,0] (row stride 64 f32).
// Strided gather: 1 useful float per 256 B.
// nt loads proven -3us (R2 vs R3): 128 MiB input thrashes 32 MiB L2; stream past it.
// This round: max TLP (1 row/thread, 2048 blocks = 8 waves/SIMD) instead of ILP,
// which R1-vs-R3 showed is neutral.

__global__ __launch_bounds__(256) void qsa_p1_kernel(
    const float* __restrict__ feat, float* __restrict__ out, int n) {
    int i = blockIdx.x * blockDim.x + threadIdx.x;
    if (i < n) {
        float th = __builtin_nontemporal_load(feat + (size_t)i * 64);
        float s = __sinf(0.5f * th);
        out[i] = s * s;
    }
}

extern "C" void kernel_launch(void* const* d_in, const int* in_sizes, int n_in,
                              void* d_out, int out_size, void* d_ws, size_t ws_size,
                              hipStream_t stream) {
    const float* feat = (const float*)d_in[0];   // [64, 8192, 64] f32
    float* out = (float*)d_out;                  // [64, 8192] f32
    int n = out_size;                            // 524288
    const int threads = 256;
    int blocks = (n + threads - 1) / threads;    // 2048
    qsa_p1_kernel<<<blocks, threads, 0, stream>>>(feat, out, n);
}

// Round 5
// 13.626 us; speedup vs baseline: 1.2332x; 1.1443x over previous
//
#include <hip/hip_runtime.h>

// QuantumSelfAttention: analytic reduction.
// P(|1> on qubit 0) = sin^2(theta0/2), theta0 = features[b,n,0] (row stride 64 f32).
// Strided gather: 1 useful float per 256 B -> one 128 B line per output.
// Proven (R1-R4 2x2): nt loads + per-thread ILP super-additive (13.7 vs 16.4 us).
// This round: ILP 8 + nt stores (pure streaming, zero L2 allocation either side).

__global__ __launch_bounds__(256) void qsa_p1_kernel(
    const float* __restrict__ feat, float* __restrict__ out) {
    // Each block: 2048 consecutive rows as 8 chunks of 256 (one per lane).
    int base = blockIdx.x * 2048 + threadIdx.x;
    float th[8];
#pragma unroll
    for (int k = 0; k < 8; ++k)
        th[k] = __builtin_nontemporal_load(feat + (size_t)(base + k * 256) * 64);
#pragma unroll
    for (int k = 0; k < 8; ++k) {
        float s = __sinf(0.5f * th[k]);
        __builtin_nontemporal_store(s * s, out + base + k * 256);
    }
}

extern "C" void kernel_launch(void* const* d_in, const int* in_sizes, int n_in,
                              void* d_out, int out_size, void* d_ws, size_t ws_size,
                              hipStream_t stream) {
    const float* feat = (const float*)d_in[0];   // [64, 8192, 64] f32
    float* out = (float*)d_out;                  // [64, 8192] f32
    int n = out_size;                            // 524288 (= 256 blocks * 2048 rows)
    const int threads = 256;
    int blocks = n / 2048;                       // 256
    qsa_p1_kernel<<<blocks, threads, 0, stream>>>(feat, out);
}